// Round 7
// baseline (403.041 us; speedup 1.0000x reference)
//
#include <hip/hip_runtime.h>
#include <hip/hip_bf16.h>

// Problem constants (fixed by the reference).
#define BB 32
#define SS 256
#define DD 256
#define UU 256
#define LL 16
#define DEG 16
#define NN (BB * SS)   // 8192 nodes
#define EE (NN * DEG)  // 131072 edges per branch
#define NSLICE 33      // slice 0 = self-loop, 1..16 = in labels, 17..32 = out labels
#define KMAIN (NSLICE * DD)   // 8448
#define KEXT 256              // ext cols: wsum/bias GEMM trick (33 used, rest 0)
#define KTOT (KMAIN + KEXT)   // 8704 = 34*256
#define KSPLIT 8
#define KS (KTOT / KSPLIT)    // 1088 = 17*64
#define TM 256                // GEMM row tile
#define TN 256                // GEMM col tile (= UU, full)
#define BK 64                 // GEMM k step
#define NTILES (KS / BK)      // 17 k-tiles per block
#define NZBLK 2048            // acc32-zeroing blocks in k_pre (2M floats / 1024)

using short8 = __attribute__((ext_vector_type(8))) short;  // 8 bf16 (4 VGPRs)
using f32x4  = __attribute__((ext_vector_type(4))) float;  // MFMA accumulator

// async global->LDS, 16B per lane, LDS dest = wave-uniform base + lane*16
#define GLDS(g, l)                                                        \
  __builtin_amdgcn_global_load_lds(                                       \
      (const __attribute__((address_space(1))) void*)(g),                 \
      (__attribute__((address_space(3))) void*)(l), 16, 0, 0)

__device__ __forceinline__ float bf2f(unsigned short v) {
  union { unsigned u; float f; } t;
  t.u = ((unsigned)v) << 16;
  return t.f;
}
__device__ __forceinline__ unsigned short f2bf(float f) {
  __hip_bfloat16 h = __float2bfloat16(f);
  return *(unsigned short*)&h;
}
__device__ __forceinline__ float sigm(float x) {
  return 1.f / (1.f + __expf(-x));
}

// ---------------------------------------------------------------------------
// K1 (merged): blocks [0,NN): prep (x cast + 3 gate dots).
// blocks [NN, NN+(NSLICE+1)*64): weight transpose + ext bias rows.
// blocks [NN+(NSLICE+1)*64, +NZBLK): zero the f32 split-K accumulator.
// ---------------------------------------------------------------------------
__global__ __launch_bounds__(256) void k_pre(
    const float* __restrict__ src, const float* __restrict__ gin,
    const float* __restrict__ gout, const float* __restrict__ gloop,
    const float* __restrict__ Vin, const float* __restrict__ Vout,
    const float* __restrict__ Wself, const float* __restrict__ b_in,
    const float* __restrict__ b_out,
    __hip_bfloat16* __restrict__ x_bf, float* __restrict__ xg_in,
    float* __restrict__ xg_out, float* __restrict__ xg_loop,
    __hip_bfloat16* __restrict__ Vt, float* __restrict__ acc32) {
  int bid = blockIdx.x;
  if (bid < NN) {
    int n = bid;
    int b = n / SS, s = n % SS;
    int d = threadIdx.x;
    float v = src[(size_t)(s * BB + b) * DD + d];
    x_bf[(size_t)n * DD + d] = __float2bfloat16(v);
    float p0 = v * gin[d], p1 = v * gout[d], p2 = v * gloop[d];
#pragma unroll
    for (int o = 32; o > 0; o >>= 1) {
      p0 += __shfl_down(p0, o);
      p1 += __shfl_down(p1, o);
      p2 += __shfl_down(p2, o);
    }
    __shared__ float r0[4], r1[4], r2[4];
    int w = threadIdx.x >> 6, lane = threadIdx.x & 63;
    if (lane == 0) { r0[w] = p0; r1[w] = p1; r2[w] = p2; }
    __syncthreads();
    if (threadIdx.x == 0) {
      xg_in[n]   = r0[0] + r0[1] + r0[2] + r0[3];
      xg_out[n]  = r1[0] + r1[1] + r1[2] + r1[3];
      xg_loop[n] = r2[0] + r2[1] + r2[2] + r2[3];
    }
    return;
  }
  int t = bid - NN;
  int z = t >> 6;                 // 0..NSLICE (+zero range beyond)
  if (z > NSLICE) {               // acc32 zeroing: 256 thr x float4 = 1024 f
    int zb = t - (NSLICE + 1) * 64;
    float4 zz = {0.f, 0.f, 0.f, 0.f};
    *(float4*)&acc32[(size_t)zb * 1024 + threadIdx.x * 4] = zz;
    return;
  }
  int rem = t & 63;
  int bx = rem & 7, by = rem >> 3;
  int tid = threadIdx.x;
  int tx = tid & 31, ty = tid >> 5;
  if (z == NSLICE) {              // ext bias rows: Vt[u][KMAIN+j] = bias_all[j][u]
    int u0 = bx * 32, j0 = by * 32;
#pragma unroll
    for (int i = 0; i < 4; i++) {
      int u = u0 + ty + i * 8, j = j0 + tx;
      float v = 0.f;
      if (j >= 1 && j <= LL)         v = b_in[(j - 1) * UU + u];
      else if (j > LL && j < NSLICE) v = b_out[(j - 1 - LL) * UU + u];
      Vt[(size_t)u * KTOT + KMAIN + j] = __float2bfloat16(v);
    }
    return;
  }
  __shared__ float tbuf[32][33];
  const float* srcM = (z == 0) ? Wself
                    : (z <= LL ? Vin  + (size_t)(z - 1)      * DD * UU
                               : Vout + (size_t)(z - 1 - LL) * DD * UU);
  int u0 = bx * 32, d0 = by * 32;
#pragma unroll
  for (int i = 0; i < 4; i++) {
    int dr = ty + i * 8;
    tbuf[dr][tx] = srcM[(size_t)(d0 + dr) * UU + u0 + tx];
  }
  __syncthreads();
#pragma unroll
  for (int i = 0; i < 4; i++) {
    int ur = ty + i * 8;
    Vt[(size_t)(u0 + ur) * KTOT + z * DD + d0 + tx] = __float2bfloat16(tbuf[tx][ur]);
  }
}

// ---------------------------------------------------------------------------
// K3: aggregation, one WAVE per dst node (round-0/1 proven; streaming writes
// of Y at near-HBM rate beat every fused-gather variant tried in R3-R5).
// ---------------------------------------------------------------------------
__global__ __launch_bounds__(64) void k_agg(
    const __hip_bfloat16* __restrict__ x,
    const float* __restrict__ xg_in, const float* __restrict__ xg_out,
    const float* __restrict__ xg_loop,
    const float* __restrict__ b_ing, const float* __restrict__ b_outg,
    const int* __restrict__ arc_in, const int* __restrict__ arc_out,
    const int* __restrict__ lab_in, const int* __restrict__ lab_out,
    const float* __restrict__ mask_in, const float* __restrict__ mask_out,
    const float* __restrict__ mask_loop,
    __hip_bfloat16* __restrict__ Y) {
  __shared__ int u_sl[32], u_src[32];
  __shared__ float u_w[32];
  __shared__ int s_sl[32], s_src[32];
  __shared__ float s_w[32];
  __shared__ float s_wsum[NSLICE];
  int n = blockIdx.x, tid = threadIdx.x;
  if (tid < 32) {
    int br = tid >> 4, k = tid & 15;
    int e = n * DEG + k;
    const int* a = br ? arc_out : arc_in;
    int l = (br ? lab_out : lab_in)[e];
    int srcn = a[e] * SS + a[EE + e];
    float g = (br ? xg_out : xg_in)[srcn] + (br ? b_outg : b_ing)[l];
    u_sl[tid] = 1 + br * LL + l;
    u_src[tid] = srcn;
    u_w[tid] = sigm(g) * (br ? mask_out : mask_in)[e];
  }
  __syncthreads();
  if (tid < 32) {
    int my = u_sl[tid];
    int rank = 0;
#pragma unroll
    for (int j = 0; j < 32; j++) {
      int oj = u_sl[j];
      rank += (oj < my || (oj == my && j < tid)) ? 1 : 0;
    }
    s_sl[rank] = my;
    s_src[rank] = u_src[tid];
    s_w[rank] = u_w[tid];
  }
  __syncthreads();

  const unsigned short* xp = (const unsigned short*)x;
  unsigned short* yp = (unsigned short*)Y;
  size_t base = (size_t)n * KTOT;
  int d4 = tid * 4;
  {
    float wl = sigm(xg_loop[n]) * mask_loop[n];
    ushort4 v = *(const ushort4*)&xp[(size_t)n * DD + d4];
    ushort4 o;
    o.x = f2bf(wl * bf2f(v.x)); o.y = f2bf(wl * bf2f(v.y));
    o.z = f2bf(wl * bf2f(v.z)); o.w = f2bf(wl * bf2f(v.w));
    *(ushort4*)&yp[base + d4] = o;
  }
  unsigned long long present = 0ull;
  float a0 = 0.f, a1 = 0.f, a2 = 0.f, a3 = 0.f, ws = 0.f;
#pragma unroll
  for (int e = 0; e < 32; e++) {
    int sl = s_sl[e];
    int srcn = s_src[e];
    float w = s_w[e];
    ushort4 v = *(const ushort4*)&xp[(size_t)srcn * DD + d4];
    a0 += w * bf2f(v.x); a1 += w * bf2f(v.y);
    a2 += w * bf2f(v.z); a3 += w * bf2f(v.w);
    ws += w;
    int slnext = (e < 31) ? s_sl[e + 1] : 999;
    if (sl != slnext) {
      ushort4 o;
      o.x = f2bf(a0); o.y = f2bf(a1); o.z = f2bf(a2); o.w = f2bf(a3);
      *(ushort4*)&yp[base + sl * DD + d4] = o;
      if (tid == 0) s_wsum[sl] = ws;
      present |= (1ull << sl);
      a0 = a1 = a2 = a3 = ws = 0.f;
    }
  }
  ushort4 zero4 = {0, 0, 0, 0};
#pragma unroll
  for (int s = 1; s < NSLICE; s++) {
    if (!((present >> s) & 1ull)) {
      *(ushort4*)&yp[base + s * DD + d4] = zero4;
      if (tid == 0) s_wsum[s] = 0.f;
    }
  }
  __syncthreads();
  {
    ushort4 o;
    unsigned short* op = (unsigned short*)&o;
#pragma unroll
    for (int c = 0; c < 4; c++) {
      int j = d4 + c;
      float v = (j >= 1 && j < NSLICE) ? s_wsum[j] : 0.f;
      op[c] = f2bf(v);
    }
    *(ushort4*)&yp[base + KMAIN + d4] = o;
  }
}

// ---------------------------------------------------------------------------
// K4: 256x256 8-phase bf16 MFMA GEMM — verbatim round-1/6 schedule (T2
// swizzle both sides, raw s_barrier, counted vmcnt, setprio, swapped-operand
// MFMA). ONE change vs R6: epilogue accumulates split-K directly into the
// f32 acc32 via hardware global_atomic_add_f32 (unsafeAtomicAdd, no return)
// — removes the 34 MB bf16 partial write + 34 MB readback, and upgrades the
// split-K sum to f32. grid (NN/TM=32, KSPLIT=8), 512 thr = 8 waves (2x4).
// ---------------------------------------------------------------------------
__global__ __launch_bounds__(512, 2) void k_gemm(
    const __hip_bfloat16* __restrict__ A, const __hip_bfloat16* __restrict__ Bt,
    float* __restrict__ acc32) {
  __shared__ __align__(16) __hip_bfloat16 As[2][TM * BK];
  __shared__ __align__(16) __hip_bfloat16 Bs[2][TN * BK];

  const int tid = threadIdx.x;
  const int w = tid >> 6, lane = tid & 63;
  const int wm = w >> 2, wn = w & 3;           // wave grid 2x4
  const int lrow = lane & 15, quad = lane >> 4;

  const int kbeg = blockIdx.y * KS;
  const int row0 = blockIdx.x * TM;

  // Staging: round r covers rows [r*64, r*64+64); thread tid writes LDS
  // bytes r*8192 + tid*16 (linear dest). Global source pre-swizzled (T2).
  const int arow = tid >> 3;                       // row within a 64-row round
  const int scol = ((tid & 7) ^ (arow & 7)) << 3;  // swizzled k-elem offset
  const __hip_bfloat16* srcA = A + (size_t)(row0 + arow) * KTOT + scol;
  const __hip_bfloat16* srcB = Bt + (size_t)arow * KTOT + scol;

  // ds_read swizzled k-slot offsets (elements) for the two k-halves
  const int sc0 = ((quad ^ (lrow & 7)) << 3);
  const int sc1 = (((4 + quad) ^ (lrow & 7)) << 3);

#define STG_A(bufi, k0, r)                                                 \
  GLDS(srcA + (size_t)((r) * 64) * KTOT + (k0),                            \
       &As[bufi][(r) * 4096 + (w << 9)])
#define STG_B(bufi, k0, r)                                                 \
  GLDS(srcB + (size_t)((r) * 64) * KTOT + (k0),                            \
       &Bs[bufi][(r) * 4096 + (w << 9)])
#define SBAR()                                                             \
  {                                                                        \
    asm volatile("" ::: "memory");                                         \
    __builtin_amdgcn_s_barrier();                                          \
    asm volatile("" ::: "memory");                                         \
  }
#define LGKM0()                                                            \
  {                                                                        \
    asm volatile("s_waitcnt lgkmcnt(0)" ::: "memory");                     \
    __builtin_amdgcn_sched_barrier(0);                                     \
  }
#define RD_A(DST, IBASE)                                                   \
  _Pragma("unroll")                                                        \
  for (int i = 0; i < 4; ++i) {                                            \
    int ro = (wm * 128 + ((IBASE) + i) * 16 + lrow) * BK;                  \
    DST[i][0] = *(const short8*)&as[ro + sc0];                             \
    DST[i][1] = *(const short8*)&as[ro + sc1];                             \
  }
#define RD_B(DST, JBASE)                                                   \
  _Pragma("unroll")                                                        \
  for (int j = 0; j < 2; ++j) {                                            \
    int ro = (wn * 64 + ((JBASE) + j) * 16 + lrow) * BK;                   \
    DST[j][0] = *(const short8*)&bs[ro + sc0];                             \
    DST[j][1] = *(const short8*)&bs[ro + sc1];                             \
  }
// operands swapped: D = B_frag x A_frag = C^T fragments (proven R2/R3/R5/R6)
#define MFMA16(AF, BF, IOFF, JOFF)                                         \
  {                                                                        \
    __builtin_amdgcn_s_setprio(1);                                         \
    _Pragma("unroll")                                                      \
    for (int i = 0; i < 4; ++i)                                            \
      _Pragma("unroll")                                                    \
      for (int j = 0; j < 2; ++j) {                                        \
        acc[(IOFF) + i][(JOFF) + j] =                                      \
            __builtin_amdgcn_mfma_f32_16x16x32_bf16(                       \
                BF[j][0], AF[i][0], acc[(IOFF) + i][(JOFF) + j], 0, 0, 0); \
        acc[(IOFF) + i][(JOFF) + j] =                                      \
            __builtin_amdgcn_mfma_f32_16x16x32_bf16(                       \
                BF[j][1], AF[i][1], acc[(IOFF) + i][(JOFF) + j], 0, 0, 0); \
      }                                                                    \
    __builtin_amdgcn_s_setprio(0);                                         \
  }

  // Prologue: stage tile0 -> buf0, tile1 -> buf1; wait tile0 (8 newest = t1).
#pragma unroll
  for (int r = 0; r < 4; ++r) STG_A(0, kbeg, r);
#pragma unroll
  for (int r = 0; r < 4; ++r) STG_B(0, kbeg, r);
#pragma unroll
  for (int r = 0; r < 4; ++r) STG_A(1, kbeg + BK, r);
#pragma unroll
  for (int r = 0; r < 4; ++r) STG_B(1, kbeg + BK, r);
  f32x4 acc[8][4] = {};
  asm volatile("s_waitcnt vmcnt(8)" ::: "memory");
  SBAR();

  for (int t = 0; t < NTILES; ++t) {
    const int bi = t & 1;
    const __hip_bfloat16* as = &As[bi][0];
    const __hip_bfloat16* bs = &Bs[bi][0];
    const bool st = (t + 2 < NTILES);
    const int kn = kbeg + (t + 2) * BK;
    short8 afA[4][2], afB[4][2], bfA[2][2], bfB[2][2];

    // ---- P1: read af[0..3], bf[0..1]; MFMA Q0 ----
    RD_A(afA, 0);
    RD_B(bfA, 0);
    SBAR();
    LGKM0();
    MFMA16(afA, bfA, 0, 0);
    SBAR();

    // ---- P2: read bf[2..3]; stage A rounds 0,2; MFMA Q1 ----
    RD_B(bfB, 2);
    if (st) { STG_A(bi, kn, 0); STG_A(bi, kn, 2); }
    SBAR();
    LGKM0();
    MFMA16(afA, bfB, 0, 2);
    SBAR();

    // ---- P3: read af[4..7]; stage B rounds 0..3; MFMA Q2 ----
    RD_A(afB, 4);
    if (st) { STG_B(bi, kn, 0); STG_B(bi, kn, 1); STG_B(bi, kn, 2); STG_B(bi, kn, 3); }
    SBAR();
    LGKM0();
    MFMA16(afB, bfA, 4, 0);
    SBAR();

    // ---- P4: stage A rounds 1,3; MFMA Q3; counted vmcnt ----
    if (st) {
      STG_A(bi, kn, 1);
      STG_A(bi, kn, 3);
      __builtin_amdgcn_sched_barrier(0);
    }
    SBAR();
    MFMA16(afB, bfB, 4, 2);
    if (st) asm volatile("s_waitcnt vmcnt(8)" ::: "memory");
    else    asm volatile("s_waitcnt vmcnt(0)" ::: "memory");
    SBAR();
  }
#undef STG_A
#undef STG_B
#undef SBAR
#undef LGKM0
#undef RD_A
#undef RD_B
#undef MFMA16

  // Swapped C/D layout: lane owns row n = ...+lrow, u = j*16 + quad*4..+3.
  // Fire-and-forget f32 hardware atomics; 4 contiguous floats per lane.
#pragma unroll
  for (int i = 0; i < 8; ++i)
#pragma unroll
    for (int j = 0; j < 4; ++j) {
      int nr = row0 + wm * 128 + i * 16 + lrow;
      int u0 = wn * 64 + j * 16 + quad * 4;
      float* p = &acc32[(size_t)nr * UU + u0];
#pragma unroll
      for (int r = 0; r < 4; ++r) unsafeAtomicAdd(p + r, acc[i][j][r]);
    }
}

// ---------------------------------------------------------------------------
// K5: relu + sent_mask + transpose from the f32 accumulator (16 MB total
// traffic vs 42 MB with bf16 partials).
// ---------------------------------------------------------------------------
__global__ __launch_bounds__(64) void k_finish(
    const float* __restrict__ acc32, const float* __restrict__ sent,
    float* __restrict__ out) {
  int n = blockIdx.x, u4 = threadIdx.x * 4;
  float4 v = *(const float4*)&acc32[(size_t)n * UU + u4];
  int s = n % SS, b = n / SS;
  float sm = sent[s * BB + b];
  float4 o;
  o.x = fmaxf(v.x, 0.f) * sm; o.y = fmaxf(v.y, 0.f) * sm;
  o.z = fmaxf(v.z, 0.f) * sm; o.w = fmaxf(v.w, 0.f) * sm;
  *(float4*)&out[((size_t)s * BB + b) * UU + u4] = o;
}

extern "C" void kernel_launch(void* const* d_in, const int* in_sizes, int n_in,
                              void* d_out, int out_size, void* d_ws, size_t ws_size,
                              hipStream_t stream) {
  const float* src      = (const float*)d_in[0];
  const float* V_in     = (const float*)d_in[1];
  const float* b_in     = (const float*)d_in[2];
  const float* V_ing    = (const float*)d_in[3];
  const float* b_ing    = (const float*)d_in[4];
  const float* V_out    = (const float*)d_in[5];
  const float* b_out    = (const float*)d_in[6];
  const float* V_outg   = (const float*)d_in[7];
  const float* b_outg   = (const float*)d_in[8];
  const float* W_self   = (const float*)d_in[9];
  const float* W_selfg  = (const float*)d_in[10];
  const int* arc_in     = (const int*)d_in[11];
  const int* arc_out    = (const int*)d_in[12];
  const int* lab_in     = (const int*)d_in[13];
  const int* lab_out    = (const int*)d_in[14];
  const float* mask_in  = (const float*)d_in[15];
  const float* mask_out = (const float*)d_in[16];
  const float* mask_loop= (const float*)d_in[17];
  const float* sent     = (const float*)d_in[18];
  float* out = (float*)d_out;

  char* ws = (char*)d_ws;
  size_t off = 0;
  auto alloc = [&](size_t bytes) -> void* {
    void* p = ws + off;
    off += (bytes + 255) & ~(size_t)255;
    return p;
  };
  __hip_bfloat16* x_bf = (__hip_bfloat16*)alloc((size_t)NN * DD * 2);       // 4 MB
  __hip_bfloat16* Vt   = (__hip_bfloat16*)alloc((size_t)UU * KTOT * 2);     // 4.5 MB
  float* xg_in   = (float*)alloc(NN * 4);
  float* xg_out  = (float*)alloc(NN * 4);
  float* xg_loop = (float*)alloc(NN * 4);
  __hip_bfloat16* Y = (__hip_bfloat16*)alloc((size_t)NN * KTOT * 2);        // 143 MB
  float* acc32   = (float*)alloc((size_t)NN * UU * 4);                      // 8 MB

  k_pre<<<NN + (NSLICE + 1) * 64 + NZBLK, 256, 0, stream>>>(
      src, V_ing, V_outg, W_selfg, V_in, V_out, W_self, b_in, b_out,
      x_bf, xg_in, xg_out, xg_loop, Vt, acc32);
  k_agg<<<NN, 64, 0, stream>>>(x_bf, xg_in, xg_out, xg_loop, b_ing, b_outg,
                               arc_in, arc_out, lab_in, lab_out,
                               mask_in, mask_out, mask_loop, Y);
  k_gemm<<<dim3(NN / TM, KSPLIT), 512, 0, stream>>>(Y, Vt, acc32);
  k_finish<<<NN, 64, 0, stream>>>(acc32, sent, out);
}

// Round 8
// 184.292 us; speedup vs baseline: 2.1870x; 2.1870x over previous
//
#include <hip/hip_runtime.h>
#include <hip/hip_bf16.h>

// Problem constants (fixed by the reference).
#define BB 32
#define SS 256
#define DD 256
#define UU 256
#define LL 16
#define DEG 16
#define NN (BB * SS)   // 8192 nodes
#define EE (NN * DEG)  // 131072 edges per branch
#define NSLICE 33      // slice 0 = self-loop, 1..16 = in labels, 17..32 = out labels
#define KMAIN (NSLICE * DD)   // 8448
#define KEXT 256              // ext cols: wsum/bias GEMM trick (33 used, rest 0)
#define KTOT (KMAIN + KEXT)   // 8704 = 34*256
#define KSPLIT 8
#define KS (KTOT / KSPLIT)    // 1088 = 17*64
#define TM 256                // GEMM row tile
#define TN 256                // GEMM col tile (= UU, full)
#define BK 64                 // GEMM k step
#define NTILES (KS / BK)      // 17 k-tiles per block

using short8 = __attribute__((ext_vector_type(8))) short;  // 8 bf16 (4 VGPRs)
using f32x4  = __attribute__((ext_vector_type(4))) float;  // MFMA accumulator

// async global->LDS, 16B per lane, LDS dest = wave-uniform base + lane*16
#define GLDS(g, l)                                                        \
  __builtin_amdgcn_global_load_lds(                                       \
      (const __attribute__((address_space(1))) void*)(g),                 \
      (__attribute__((address_space(3))) void*)(l), 16, 0, 0)

__device__ __forceinline__ float bf2f(unsigned short v) {
  union { unsigned u; float f; } t;
  t.u = ((unsigned)v) << 16;
  return t.f;
}
__device__ __forceinline__ unsigned short f2bf(float f) {
  __hip_bfloat16 h = __float2bfloat16(f);
  return *(unsigned short*)&h;
}
__device__ __forceinline__ float sigm(float x) {
  return 1.f / (1.f + __expf(-x));
}

// ---------------------------------------------------------------------------
// K1 (merged): blocks [0,NN): prep (x cast + 3 gate dots).
// blocks [NN, NN+(NSLICE+1)*64): weight transpose + ext bias rows.
// Verbatim from the 184.9 us build (round 1).
// ---------------------------------------------------------------------------
__global__ __launch_bounds__(256) void k_pre(
    const float* __restrict__ src, const float* __restrict__ gin,
    const float* __restrict__ gout, const float* __restrict__ gloop,
    const float* __restrict__ Vin, const float* __restrict__ Vout,
    const float* __restrict__ Wself, const float* __restrict__ b_in,
    const float* __restrict__ b_out,
    __hip_bfloat16* __restrict__ x_bf, float* __restrict__ xg_in,
    float* __restrict__ xg_out, float* __restrict__ xg_loop,
    __hip_bfloat16* __restrict__ Vt) {
  int bid = blockIdx.x;
  if (bid < NN) {
    int n = bid;
    int b = n / SS, s = n % SS;
    int d = threadIdx.x;
    float v = src[(size_t)(s * BB + b) * DD + d];
    x_bf[(size_t)n * DD + d] = __float2bfloat16(v);
    float p0 = v * gin[d], p1 = v * gout[d], p2 = v * gloop[d];
#pragma unroll
    for (int o = 32; o > 0; o >>= 1) {
      p0 += __shfl_down(p0, o);
      p1 += __shfl_down(p1, o);
      p2 += __shfl_down(p2, o);
    }
    __shared__ float r0[4], r1[4], r2[4];
    int w = threadIdx.x >> 6, lane = threadIdx.x & 63;
    if (lane == 0) { r0[w] = p0; r1[w] = p1; r2[w] = p2; }
    __syncthreads();
    if (threadIdx.x == 0) {
      xg_in[n]   = r0[0] + r0[1] + r0[2] + r0[3];
      xg_out[n]  = r1[0] + r1[1] + r1[2] + r1[3];
      xg_loop[n] = r2[0] + r2[1] + r2[2] + r2[3];
    }
    return;
  }
  int t = bid - NN;
  int z = t >> 6;                 // 0..NSLICE
  int rem = t & 63;
  int bx = rem & 7, by = rem >> 3;
  int tid = threadIdx.x;
  int tx = tid & 31, ty = tid >> 5;
  if (z == NSLICE) {              // ext bias rows: Vt[u][KMAIN+j] = bias_all[j][u]
    int u0 = bx * 32, j0 = by * 32;
#pragma unroll
    for (int i = 0; i < 4; i++) {
      int u = u0 + ty + i * 8, j = j0 + tx;
      float v = 0.f;
      if (j >= 1 && j <= LL)         v = b_in[(j - 1) * UU + u];
      else if (j > LL && j < NSLICE) v = b_out[(j - 1 - LL) * UU + u];
      Vt[(size_t)u * KTOT + KMAIN + j] = __float2bfloat16(v);
    }
    return;
  }
  __shared__ float tbuf[32][33];
  const float* srcM = (z == 0) ? Wself
                    : (z <= LL ? Vin  + (size_t)(z - 1)      * DD * UU
                               : Vout + (size_t)(z - 1 - LL) * DD * UU);
  int u0 = bx * 32, d0 = by * 32;
#pragma unroll
  for (int i = 0; i < 4; i++) {
    int dr = ty + i * 8;
    tbuf[dr][tx] = srcM[(size_t)(d0 + dr) * UU + u0 + tx];
  }
  __syncthreads();
#pragma unroll
  for (int i = 0; i < 4; i++) {
    int ur = ty + i * 8;
    Vt[(size_t)(u0 + ur) * KTOT + z * DD + d0 + tx] = __float2bfloat16(tbuf[tx][ur]);
  }
}

// ---------------------------------------------------------------------------
// K3: aggregation, one WAVE per dst node (round-0/1 proven; streaming writes
// of Y at near-HBM rate beat every fused-gather variant tried in R3-R5).
// ---------------------------------------------------------------------------
__global__ __launch_bounds__(64) void k_agg(
    const __hip_bfloat16* __restrict__ x,
    const float* __restrict__ xg_in, const float* __restrict__ xg_out,
    const float* __restrict__ xg_loop,
    const float* __restrict__ b_ing, const float* __restrict__ b_outg,
    const int* __restrict__ arc_in, const int* __restrict__ arc_out,
    const int* __restrict__ lab_in, const int* __restrict__ lab_out,
    const float* __restrict__ mask_in, const float* __restrict__ mask_out,
    const float* __restrict__ mask_loop,
    __hip_bfloat16* __restrict__ Y) {
  __shared__ int u_sl[32], u_src[32];
  __shared__ float u_w[32];
  __shared__ int s_sl[32], s_src[32];
  __shared__ float s_w[32];
  __shared__ float s_wsum[NSLICE];
  int n = blockIdx.x, tid = threadIdx.x;
  if (tid < 32) {
    int br = tid >> 4, k = tid & 15;
    int e = n * DEG + k;
    const int* a = br ? arc_out : arc_in;
    int l = (br ? lab_out : lab_in)[e];
    int srcn = a[e] * SS + a[EE + e];
    float g = (br ? xg_out : xg_in)[srcn] + (br ? b_outg : b_ing)[l];
    u_sl[tid] = 1 + br * LL + l;
    u_src[tid] = srcn;
    u_w[tid] = sigm(g) * (br ? mask_out : mask_in)[e];
  }
  __syncthreads();
  if (tid < 32) {
    int my = u_sl[tid];
    int rank = 0;
#pragma unroll
    for (int j = 0; j < 32; j++) {
      int oj = u_sl[j];
      rank += (oj < my || (oj == my && j < tid)) ? 1 : 0;
    }
    s_sl[rank] = my;
    s_src[rank] = u_src[tid];
    s_w[rank] = u_w[tid];
  }
  __syncthreads();

  const unsigned short* xp = (const unsigned short*)x;
  unsigned short* yp = (unsigned short*)Y;
  size_t base = (size_t)n * KTOT;
  int d4 = tid * 4;
  {
    float wl = sigm(xg_loop[n]) * mask_loop[n];
    ushort4 v = *(const ushort4*)&xp[(size_t)n * DD + d4];
    ushort4 o;
    o.x = f2bf(wl * bf2f(v.x)); o.y = f2bf(wl * bf2f(v.y));
    o.z = f2bf(wl * bf2f(v.z)); o.w = f2bf(wl * bf2f(v.w));
    *(ushort4*)&yp[base + d4] = o;
  }
  unsigned long long present = 0ull;
  float a0 = 0.f, a1 = 0.f, a2 = 0.f, a3 = 0.f, ws = 0.f;
#pragma unroll
  for (int e = 0; e < 32; e++) {
    int sl = s_sl[e];
    int srcn = s_src[e];
    float w = s_w[e];
    ushort4 v = *(const ushort4*)&xp[(size_t)srcn * DD + d4];
    a0 += w * bf2f(v.x); a1 += w * bf2f(v.y);
    a2 += w * bf2f(v.z); a3 += w * bf2f(v.w);
    ws += w;
    int slnext = (e < 31) ? s_sl[e + 1] : 999;
    if (sl != slnext) {
      ushort4 o;
      o.x = f2bf(a0); o.y = f2bf(a1); o.z = f2bf(a2); o.w = f2bf(a3);
      *(ushort4*)&yp[base + sl * DD + d4] = o;
      if (tid == 0) s_wsum[sl] = ws;
      present |= (1ull << sl);
      a0 = a1 = a2 = a3 = ws = 0.f;
    }
  }
  ushort4 zero4 = {0, 0, 0, 0};
#pragma unroll
  for (int s = 1; s < NSLICE; s++) {
    if (!((present >> s) & 1ull)) {
      *(ushort4*)&yp[base + s * DD + d4] = zero4;
      if (tid == 0) s_wsum[s] = 0.f;
    }
  }
  __syncthreads();
  {
    ushort4 o;
    unsigned short* op = (unsigned short*)&o;
#pragma unroll
    for (int c = 0; c < 4; c++) {
      int j = d4 + c;
      float v = (j >= 1 && j < NSLICE) ? s_wsum[j] : 0.f;
      op[c] = f2bf(v);
    }
    *(ushort4*)&yp[base + KMAIN + d4] = o;
  }
}

// ---------------------------------------------------------------------------
// K4: 256x256 8-phase bf16 MFMA GEMM — VERBATIM round-1 build (measured
// 44.8 us there; best of all k_gemm variants tried). T2 XOR-swizzle both
// sides, raw s_barrier, counted vmcnt(8), setprio, unswapped operands,
// scalar-store epilogue. grid (NN/TM=32, KSPLIT=8), 512 thr = 8 waves (2x4).
// ---------------------------------------------------------------------------
__global__ __launch_bounds__(512, 2) void k_gemm(
    const __hip_bfloat16* __restrict__ A, const __hip_bfloat16* __restrict__ Bt,
    __hip_bfloat16* __restrict__ partial) {
  __shared__ __align__(16) __hip_bfloat16 As[2][TM * BK];
  __shared__ __align__(16) __hip_bfloat16 Bs[2][TN * BK];

  const int tid = threadIdx.x;
  const int w = tid >> 6, lane = tid & 63;
  const int wm = w >> 2, wn = w & 3;           // wave grid 2x4
  const int lrow = lane & 15, quad = lane >> 4;

  __hip_bfloat16* P = partial + (size_t)blockIdx.y * NN * UU;
  const int kbeg = blockIdx.y * KS;
  const int row0 = blockIdx.x * TM;

  // Staging: round r covers rows [r*64, r*64+64); thread tid writes LDS
  // bytes r*8192 + tid*16 (linear dest). Global source pre-swizzled (T2).
  const int arow = tid >> 3;                       // row within a 64-row round
  const int scol = ((tid & 7) ^ (arow & 7)) << 3;  // swizzled k-elem offset
  const __hip_bfloat16* srcA = A + (size_t)(row0 + arow) * KTOT + scol;
  const __hip_bfloat16* srcB = Bt + (size_t)arow * KTOT + scol;

  // ds_read swizzled k-slot offsets (elements) for the two k-halves
  const int sc0 = ((quad ^ (lrow & 7)) << 3);
  const int sc1 = (((4 + quad) ^ (lrow & 7)) << 3);

#define STG_A(bufi, k0, r)                                                 \
  GLDS(srcA + (size_t)((r) * 64) * KTOT + (k0),                            \
       &As[bufi][(r) * 4096 + (w << 9)])
#define STG_B(bufi, k0, r)                                                 \
  GLDS(srcB + (size_t)((r) * 64) * KTOT + (k0),                            \
       &Bs[bufi][(r) * 4096 + (w << 9)])
#define SBAR()                                                             \
  {                                                                        \
    asm volatile("" ::: "memory");                                         \
    __builtin_amdgcn_s_barrier();                                          \
    asm volatile("" ::: "memory");                                         \
  }
#define LGKM0()                                                            \
  {                                                                        \
    asm volatile("s_waitcnt lgkmcnt(0)" ::: "memory");                     \
    __builtin_amdgcn_sched_barrier(0);                                     \
  }
#define RD_A(DST, IBASE)                                                   \
  _Pragma("unroll")                                                        \
  for (int i = 0; i < 4; ++i) {                                            \
    int ro = (wm * 128 + ((IBASE) + i) * 16 + lrow) * BK;                  \
    DST[i][0] = *(const short8*)&as[ro + sc0];                             \
    DST[i][1] = *(const short8*)&as[ro + sc1];                             \
  }
#define RD_B(DST, JBASE)                                                   \
  _Pragma("unroll")                                                        \
  for (int j = 0; j < 2; ++j) {                                            \
    int ro = (wn * 64 + ((JBASE) + j) * 16 + lrow) * BK;                   \
    DST[j][0] = *(const short8*)&bs[ro + sc0];                             \
    DST[j][1] = *(const short8*)&bs[ro + sc1];                             \
  }
#define MFMA16(AF, BF, IOFF, JOFF)                                         \
  {                                                                        \
    __builtin_amdgcn_s_setprio(1);                                         \
    _Pragma("unroll")                                                      \
    for (int i = 0; i < 4; ++i)                                            \
      _Pragma("unroll")                                                    \
      for (int j = 0; j < 2; ++j) {                                        \
        acc[(IOFF) + i][(JOFF) + j] =                                      \
            __builtin_amdgcn_mfma_f32_16x16x32_bf16(                       \
                AF[i][0], BF[j][0], acc[(IOFF) + i][(JOFF) + j], 0, 0, 0); \
        acc[(IOFF) + i][(JOFF) + j] =                                      \
            __builtin_amdgcn_mfma_f32_16x16x32_bf16(                       \
                AF[i][1], BF[j][1], acc[(IOFF) + i][(JOFF) + j], 0, 0, 0); \
      }                                                                    \
    __builtin_amdgcn_s_setprio(0);                                         \
  }

  // Prologue: stage tile0 -> buf0, tile1 -> buf1; wait tile0 (8 newest = t1).
#pragma unroll
  for (int r = 0; r < 4; ++r) STG_A(0, kbeg, r);
#pragma unroll
  for (int r = 0; r < 4; ++r) STG_B(0, kbeg, r);
#pragma unroll
  for (int r = 0; r < 4; ++r) STG_A(1, kbeg + BK, r);
#pragma unroll
  for (int r = 0; r < 4; ++r) STG_B(1, kbeg + BK, r);
  f32x4 acc[8][4] = {};
  asm volatile("s_waitcnt vmcnt(8)" ::: "memory");
  SBAR();

  for (int t = 0; t < NTILES; ++t) {
    const int bi = t & 1;
    const __hip_bfloat16* as = &As[bi][0];
    const __hip_bfloat16* bs = &Bs[bi][0];
    const bool st = (t + 2 < NTILES);
    const int kn = kbeg + (t + 2) * BK;
    short8 afA[4][2], afB[4][2], bfA[2][2], bfB[2][2];

    // ---- P1: read af[0..3], bf[0..1]; MFMA Q0 ----
    RD_A(afA, 0);
    RD_B(bfA, 0);
    SBAR();
    LGKM0();
    MFMA16(afA, bfA, 0, 0);
    SBAR();

    // ---- P2: read bf[2..3]; stage A rounds 0,2; MFMA Q1 ----
    RD_B(bfB, 2);
    if (st) { STG_A(bi, kn, 0); STG_A(bi, kn, 2); }
    SBAR();
    LGKM0();
    MFMA16(afA, bfB, 0, 2);
    SBAR();

    // ---- P3: read af[4..7]; stage B rounds 0..3; MFMA Q2 ----
    RD_A(afB, 4);
    if (st) { STG_B(bi, kn, 0); STG_B(bi, kn, 1); STG_B(bi, kn, 2); STG_B(bi, kn, 3); }
    SBAR();
    LGKM0();
    MFMA16(afB, bfA, 4, 0);
    SBAR();

    // ---- P4: stage A rounds 1,3; MFMA Q3; counted vmcnt ----
    if (st) {
      STG_A(bi, kn, 1);
      STG_A(bi, kn, 3);
      __builtin_amdgcn_sched_barrier(0);
    }
    SBAR();
    MFMA16(afB, bfB, 4, 2);
    if (st) asm volatile("s_waitcnt vmcnt(8)" ::: "memory");
    else    asm volatile("s_waitcnt vmcnt(0)" ::: "memory");
    SBAR();
  }
#undef STG_A
#undef STG_B
#undef SBAR
#undef LGKM0
#undef RD_A
#undef RD_B
#undef MFMA16

  // C/D layout (m89/m91): col = lane&15, row = quad*4 + r
#pragma unroll
  for (int i = 0; i < 8; ++i)
#pragma unroll
    for (int j = 0; j < 4; ++j) {
      int col = wn * 64 + j * 16 + lrow;
      int rowb = row0 + wm * 128 + i * 16 + quad * 4;
#pragma unroll
      for (int r = 0; r < 4; ++r)
        P[(size_t)(rowb + r) * UU + col] = __float2bfloat16(acc[i][j][r]);
    }
}

// ---------------------------------------------------------------------------
// K5: reduce KSPLIT bf16 partials + relu + sent_mask + transpose.
// Widened: 256-thread blocks, 4 nodes each (2048 blocks vs 8192) — same
// per-thread work, less tiny-block dispatch overhead.
// ---------------------------------------------------------------------------
__global__ __launch_bounds__(256) void k_finish(
    const __hip_bfloat16* __restrict__ partial, const float* __restrict__ sent,
    float* __restrict__ out) {
  int n = blockIdx.x * 4 + (threadIdx.x >> 6);
  int u4 = (threadIdx.x & 63) * 4;
  size_t idx = (size_t)n * UU + u4;
  const unsigned short* pp = (const unsigned short*)partial;
  float a0 = 0.f, a1 = 0.f, a2 = 0.f, a3 = 0.f;
#pragma unroll
  for (int z = 0; z < KSPLIT; z++) {
    ushort4 v = *(const ushort4*)&pp[(size_t)z * NN * UU + idx];
    a0 += bf2f(v.x); a1 += bf2f(v.y); a2 += bf2f(v.z); a3 += bf2f(v.w);
  }
  int s = n % SS, b = n / SS;
  float sm = sent[s * BB + b];
  float4 o;
  o.x = fmaxf(a0, 0.f) * sm; o.y = fmaxf(a1, 0.f) * sm;
  o.z = fmaxf(a2, 0.f) * sm; o.w = fmaxf(a3, 0.f) * sm;
  *(float4*)&out[((size_t)s * BB + b) * UU + u4] = o;
}

extern "C" void kernel_launch(void* const* d_in, const int* in_sizes, int n_in,
                              void* d_out, int out_size, void* d_ws, size_t ws_size,
                              hipStream_t stream) {
  const float* src      = (const float*)d_in[0];
  const float* V_in     = (const float*)d_in[1];
  const float* b_in     = (const float*)d_in[2];
  const float* V_ing    = (const float*)d_in[3];
  const float* b_ing    = (const float*)d_in[4];
  const float* V_out    = (const float*)d_in[5];
  const float* b_out    = (const float*)d_in[6];
  const float* V_outg   = (const float*)d_in[7];
  const float* b_outg   = (const float*)d_in[8];
  const float* W_self   = (const float*)d_in[9];
  const float* W_selfg  = (const float*)d_in[10];
  const int* arc_in     = (const int*)d_in[11];
  const int* arc_out    = (const int*)d_in[12];
  const int* lab_in     = (const int*)d_in[13];
  const int* lab_out    = (const int*)d_in[14];
  const float* mask_in  = (const float*)d_in[15];
  const float* mask_out = (const float*)d_in[16];
  const float* mask_loop= (const float*)d_in[17];
  const float* sent     = (const float*)d_in[18];
  float* out = (float*)d_out;

  char* ws = (char*)d_ws;
  size_t off = 0;
  auto alloc = [&](size_t bytes) -> void* {
    void* p = ws + off;
    off += (bytes + 255) & ~(size_t)255;
    return p;
  };
  __hip_bfloat16* x_bf = (__hip_bfloat16*)alloc((size_t)NN * DD * 2);       // 4 MB
  __hip_bfloat16* Vt   = (__hip_bfloat16*)alloc((size_t)UU * KTOT * 2);     // 4.5 MB
  float* xg_in   = (float*)alloc(NN * 4);
  float* xg_out  = (float*)alloc(NN * 4);
  float* xg_loop = (float*)alloc(NN * 4);
  __hip_bfloat16* Y = (__hip_bfloat16*)alloc((size_t)NN * KTOT * 2);        // 143 MB
  __hip_bfloat16* partial =
      (__hip_bfloat16*)alloc((size_t)KSPLIT * NN * UU * 2);                 // 34 MB

  k_pre<<<NN + (NSLICE + 1) * 64, 256, 0, stream>>>(
      src, V_ing, V_outg, W_selfg, V_in, V_out, W_self, b_in, b_out,
      x_bf, xg_in, xg_out, xg_loop, Vt);
  k_agg<<<NN, 64, 0, stream>>>(x_bf, xg_in, xg_out, xg_loop, b_ing, b_outg,
                               arc_in, arc_out, lab_in, lab_out,
                               mask_in, mask_out, mask_loop, Y);
  k_gemm<<<dim3(NN / TM, KSPLIT), 512, 0, stream>>>(Y, Vt, partial);
  k_finish<<<NN / 4, 256, 0, stream>>>(partial, sent, out);
}